// Round 1
// baseline (648.857 us; speedup 1.0000x reference)
//
#include <hip/hip_runtime.h>

#define LRELU_SLOPE 0.2f
#define BN_EPS 1e-5f

// ---------------- CSR build (by dst) ----------------
__global__ void count_dst_kernel(const int* __restrict__ dst, int* __restrict__ counts, int E) {
    int e = blockIdx.x * blockDim.x + threadIdx.x;
    if (e < E) atomicAdd(&counts[dst[e]], 1);
}

// exclusive scan of counts[n] -> offs[n], offs[n]=total. Single block, 256 threads, 1024 elems/iter.
__global__ void scan_kernel(const int* __restrict__ counts, int* __restrict__ offs, int n, int total) {
    __shared__ int wsum[4];
    __shared__ int carrySh;
    if (threadIdx.x == 0) carrySh = 0;
    __syncthreads();
    const int lane = threadIdx.x & 63;
    const int wv = threadIdx.x >> 6;
    for (int base = 0; base < n; base += 1024) {
        int i0 = base + (int)threadIdx.x * 4;
        int v0 = (i0 + 0 < n) ? counts[i0 + 0] : 0;
        int v1 = (i0 + 1 < n) ? counts[i0 + 1] : 0;
        int v2 = (i0 + 2 < n) ? counts[i0 + 2] : 0;
        int v3 = (i0 + 3 < n) ? counts[i0 + 3] : 0;
        int s4 = v0 + v1 + v2 + v3;
        int s = s4;
        #pragma unroll
        for (int off = 1; off < 64; off <<= 1) {
            int t = __shfl_up(s, off, 64);
            if (lane >= off) s += t;
        }
        if (lane == 63) wsum[wv] = s;
        __syncthreads();
        int carry = carrySh;
        int wpre = 0;
        for (int w = 0; w < wv; ++w) wpre += wsum[w];
        int excl = carry + wpre + s - s4;
        if (i0 + 0 < n) offs[i0 + 0] = excl;
        excl += v0;
        if (i0 + 1 < n) offs[i0 + 1] = excl;
        excl += v1;
        if (i0 + 2 < n) offs[i0 + 2] = excl;
        excl += v2;
        if (i0 + 3 < n) offs[i0 + 3] = excl;
        __syncthreads();
        if (threadIdx.x == 255) carrySh = carry + wpre + s;
        __syncthreads();
    }
    if (threadIdx.x == 0) offs[n] = total;
}

__global__ void scatter_kernel(const int* __restrict__ src, const int* __restrict__ dst,
                               const int* __restrict__ offs, int* __restrict__ cursor,
                               int* __restrict__ esrc, int E) {
    int e = blockIdx.x * blockDim.x + threadIdx.x;
    if (e < E) {
        int d = dst[e];
        int pos = offs[d] + atomicAdd(&cursor[d], 1);
        esrc[pos] = src[e];
    }
}

// ---------------- dual GEMM: out[:, 0:NCH] = X@Wl+bl ; out[:, NCH:2*NCH] = X@Wr+br ----------------
// 64x64 tile, 256 threads, 4x4 register tile, fp32 vector FMA.
template <int K, int NCH>
__global__ __launch_bounds__(256) void dual_gemm_kernel(
    const float* __restrict__ X,
    const float* __restrict__ Wl, const float* __restrict__ bl,
    const float* __restrict__ Wr, const float* __restrict__ br,
    float* __restrict__ out, int N) {
    constexpr int ST = 2 * NCH;
    const int colBase = blockIdx.y * 64;
    const float* W = (colBase < NCH) ? Wl : Wr;
    const float* bias = (colBase < NCH) ? bl : br;
    const int wcol = (colBase < NCH) ? colBase : colBase - NCH;
    const int rowBase = blockIdx.x * 64;

    __shared__ float xs[32][68];  // [k][row]
    __shared__ float wsh[32][68]; // [k][col]

    const int tid = threadIdx.x;
    const int tc = tid & 15;  // col group
    const int tr = tid >> 4;  // row group
    float acc[4][4] = {};

    for (int k0 = 0; k0 < K; k0 += 32) {
        // load X tile (64 rows x 32 k), float4 along k
        {
            int r = tid >> 3;          // 0..31
            int kq = (tid & 7) * 4;    // 0,4,..,28
            #pragma unroll
            for (int rp = 0; rp < 64; rp += 32) {
                int gr = rowBase + rp + r;
                float4 v = make_float4(0.f, 0.f, 0.f, 0.f);
                if (gr < N) v = *reinterpret_cast<const float4*>(&X[(size_t)gr * K + k0 + kq]);
                xs[kq + 0][rp + r] = v.x;
                xs[kq + 1][rp + r] = v.y;
                xs[kq + 2][rp + r] = v.z;
                xs[kq + 3][rp + r] = v.w;
            }
        }
        // load W tile (32 k x 64 cols), float4 along cols
        {
            int k = tid >> 4;          // 0..15
            int c4 = (tid & 15) * 4;   // 0..60
            #pragma unroll
            for (int kp = 0; kp < 32; kp += 16) {
                float4 wv = *reinterpret_cast<const float4*>(&W[(size_t)(k0 + kp + k) * NCH + wcol + c4]);
                wsh[kp + k][c4 + 0] = wv.x;
                wsh[kp + k][c4 + 1] = wv.y;
                wsh[kp + k][c4 + 2] = wv.z;
                wsh[kp + k][c4 + 3] = wv.w;
            }
        }
        __syncthreads();
        #pragma unroll
        for (int k = 0; k < 32; ++k) {
            float4 av = *reinterpret_cast<const float4*>(&xs[k][tr * 4]);
            float4 bv = *reinterpret_cast<const float4*>(&wsh[k][tc * 4]);
            float a[4] = {av.x, av.y, av.z, av.w};
            float b[4] = {bv.x, bv.y, bv.z, bv.w};
            #pragma unroll
            for (int i = 0; i < 4; ++i)
                #pragma unroll
                for (int j = 0; j < 4; ++j) acc[i][j] += a[i] * b[j];
        }
        __syncthreads();
    }
    #pragma unroll
    for (int i = 0; i < 4; ++i) {
        int gr = rowBase + tr * 4 + i;
        if (gr < N) {
            float4 o;
            o.x = acc[i][0] + bias[wcol + tc * 4 + 0];
            o.y = acc[i][1] + bias[wcol + tc * 4 + 1];
            o.z = acc[i][2] + bias[wcol + tc * 4 + 2];
            o.w = acc[i][3] + bias[wcol + tc * 4 + 3];
            *reinterpret_cast<float4*>(&out[(size_t)gr * ST + colBase + tc * 4]) = o;
        }
    }
}

// ---------------- GATv2 aggregation: one wave per dst node ----------------
// proj row layout: [xl (H*64) | xr (H*64)]. Single pass, exp without max-sub
// (logits are O(1): mathematically identical alpha, no overflow possible here).
template <int H>
__global__ __launch_bounds__(256) void gat_agg_kernel(
    const float* __restrict__ proj,
    const int* __restrict__ offs, const int* __restrict__ esrc,
    const float* __restrict__ att,   // [H,64]
    const float* __restrict__ bias,  // [H*64]
    float* __restrict__ outh,        // [N, H*64] (relu applied)
    int N) {
    constexpr int C = 64;
    constexpr int HC = H * C;
    constexpr int ST = 2 * HC;
    const int lane = threadIdx.x & 63;
    const int node = blockIdx.x * 4 + (threadIdx.x >> 6);
    if (node >= N) return;

    float xr[H], attv[H], acc[H], denom[H];
    #pragma unroll
    for (int h = 0; h < H; ++h) {
        xr[h] = proj[(size_t)node * ST + HC + h * C + lane];
        attv[h] = att[h * C + lane];
        acc[h] = 0.f;
        denom[h] = 0.f;
    }
    const int beg = offs[node];
    const int end = offs[node + 1];
    for (int i = beg - 1; i < end; ++i) {  // i == beg-1 -> self loop
        const int src = (i < beg) ? node : esrc[i];
        float xl[H], s[H];
        #pragma unroll
        for (int h = 0; h < H; ++h) {
            xl[h] = proj[(size_t)src * ST + h * C + lane];
            float t = xl[h] + xr[h];
            t = (t > 0.f) ? t : LRELU_SLOPE * t;
            s[h] = t * attv[h];
        }
        #pragma unroll
        for (int off = 32; off > 0; off >>= 1) {
            #pragma unroll
            for (int h = 0; h < H; ++h) s[h] += __shfl_xor(s[h], off, 64);
        }
        #pragma unroll
        for (int h = 0; h < H; ++h) {
            float p = __expf(s[h]);  // s[h] == full logit (broadcast to all lanes)
            denom[h] += p;
            acc[h] += p * xl[h];
        }
    }
    #pragma unroll
    for (int h = 0; h < H; ++h) {
        float v = acc[h] / denom[h] + bias[h * C + lane];
        outh[(size_t)node * HC + h * C + lane] = (v > 0.f) ? v : 0.f;
    }
}

// ---------------- BatchNorm over nodes ----------------
template <int CH>
__global__ void bn_stats_kernel(const float* __restrict__ h, float* __restrict__ stats, int N) {
    const int c = threadIdx.x;  // blockDim.x == CH
    float s = 0.f, q = 0.f;
    for (int r = blockIdx.x; r < N; r += gridDim.x) {
        float v = h[(size_t)r * CH + c];
        s += v;
        q += v * v;
    }
    atomicAdd(&stats[c], s);
    atomicAdd(&stats[CH + c], q);
}

template <int CH>
__global__ void bn_finalize_kernel(const float* __restrict__ stats,
                                   const float* __restrict__ gamma, const float* __restrict__ beta,
                                   float* __restrict__ ss, int N) {
    int c = threadIdx.x;
    float mu = stats[c] / (float)N;
    float var = stats[CH + c] / (float)N - mu * mu;
    float sc = gamma[c] * rsqrtf(var + BN_EPS);
    ss[c] = sc;
    ss[CH + c] = beta[c] - mu * sc;
}

template <int CH>
__global__ void bn_apply4_kernel(float* __restrict__ h, const float* __restrict__ ss, size_t total4) {
    size_t i = (size_t)blockIdx.x * blockDim.x + threadIdx.x;
    if (i >= total4) return;
    size_t e = i * 4;
    int c = (int)(e % CH);
    float4 v = *reinterpret_cast<float4*>(&h[e]);
    v.x = v.x * ss[c + 0] + ss[CH + c + 0];
    v.y = v.y * ss[c + 1] + ss[CH + c + 1];
    v.z = v.z * ss[c + 2] + ss[CH + c + 2];
    v.w = v.w * ss[c + 3] + ss[CH + c + 3];
    *reinterpret_cast<float4*>(&h[e]) = v;
}

extern "C" void kernel_launch(void* const* d_in, const int* in_sizes, int n_in,
                              void* d_out, int out_size, void* d_ws, size_t ws_size,
                              hipStream_t stream) {
    const float* x     = (const float*)d_in[0];
    const int*   eidx  = (const int*)d_in[1];
    const float* Wl0   = (const float*)d_in[2];
    const float* bl0   = (const float*)d_in[3];
    const float* Wr0   = (const float*)d_in[4];
    const float* br0   = (const float*)d_in[5];
    const float* att0  = (const float*)d_in[6];
    const float* bias0 = (const float*)d_in[7];
    const float* g0    = (const float*)d_in[8];
    const float* be0   = (const float*)d_in[9];
    const float* Wl1   = (const float*)d_in[10];
    const float* bl1   = (const float*)d_in[11];
    const float* Wr1   = (const float*)d_in[12];
    const float* br1   = (const float*)d_in[13];
    const float* att1  = (const float*)d_in[14];
    const float* bias1 = (const float*)d_in[15];
    const float* g1    = (const float*)d_in[16];
    const float* be1   = (const float*)d_in[17];

    const int N = in_sizes[0] / 128;
    const int E = in_sizes[1] / 2;
    const int* srcIdx = eidx;
    const int* dstIdx = eidx + E;

    // workspace carve (peak ~119 MB)
    char* base = (char*)d_ws;
    auto alloc = [&](size_t bytes) {
        char* p = base;
        base += (bytes + 255) & ~(size_t)255;
        return p;
    };
    float* proj  = (float*)alloc((size_t)N * 384 * 4);  // layer0 [xl|xr]; reused for layer1 (N*128)
    float* h0    = (float*)alloc((size_t)N * 192 * 4);
    int*   offs  = (int*)alloc((size_t)(N + 1) * 4);
    int*   cursor= (int*)alloc((size_t)N * 4);
    int*   esrc  = (int*)alloc((size_t)E * 4);
    float* stats = (float*)alloc(384 * 4);
    float* ss    = (float*)alloc(384 * 4);

    // ---- CSR by dst (order within a node is irrelevant to the math) ----
    hipMemsetAsync(cursor, 0, (size_t)N * 4, stream);
    count_dst_kernel<<<(E + 255) / 256, 256, 0, stream>>>(dstIdx, cursor, E);
    scan_kernel<<<1, 256, 0, stream>>>(cursor, offs, N, E);
    hipMemsetAsync(cursor, 0, (size_t)N * 4, stream);
    scatter_kernel<<<(E + 255) / 256, 256, 0, stream>>>(srcIdx, dstIdx, offs, cursor, esrc, E);

    // ---- layer 0: 128 -> 3 heads x 64 (concat 192) ----
    {
        dim3 grid((N + 63) / 64, 6);
        dual_gemm_kernel<128, 192><<<grid, 256, 0, stream>>>(x, Wl0, bl0, Wr0, br0, proj, N);
    }
    gat_agg_kernel<3><<<(N + 3) / 4, 256, 0, stream>>>(proj, offs, esrc, att0, bias0, h0, N);
    hipMemsetAsync(stats, 0, 384 * 4, stream);
    bn_stats_kernel<192><<<256, 192, 0, stream>>>(h0, stats, N);
    bn_finalize_kernel<192><<<1, 192, 0, stream>>>(stats, g0, be0, ss, N);
    {
        size_t tot4 = (size_t)N * 192 / 4;
        bn_apply4_kernel<192><<<(unsigned)((tot4 + 255) / 256), 256, 0, stream>>>(h0, ss, tot4);
    }

    // ---- layer 1: 192 -> 1 head x 64 ----
    {
        dim3 grid((N + 63) / 64, 2);
        dual_gemm_kernel<192, 64><<<grid, 256, 0, stream>>>(h0, Wl1, bl1, Wr1, br1, proj, N);
    }
    float* out = (float*)d_out;
    gat_agg_kernel<1><<<(N + 3) / 4, 256, 0, stream>>>(proj, offs, esrc, att1, bias1, out, N);
    hipMemsetAsync(stats, 0, 384 * 4, stream);
    bn_stats_kernel<64><<<256, 64, 0, stream>>>(out, stats, N);
    bn_finalize_kernel<64><<<1, 64, 0, stream>>>(stats, g1, be1, ss, N);
    {
        size_t tot4 = (size_t)N * 64 / 4;
        bn_apply4_kernel<64><<<(unsigned)((tot4 + 255) / 256), 256, 0, stream>>>(out, ss, tot4);
    }
}

// Round 2
// 618.303 us; speedup vs baseline: 1.0494x; 1.0494x over previous
//
#include <hip/hip_runtime.h>
#include <hip/hip_bf16.h>

#define LRELU_SLOPE 0.2f
#define BN_EPS 1e-5f

static __device__ __forceinline__ unsigned short f2bf(float f) {
    __hip_bfloat16 b = __float2bfloat16(f);
    return *reinterpret_cast<unsigned short*>(&b);
}
static __device__ __forceinline__ float bf2f(unsigned short u) {
    return __uint_as_float(((unsigned)u) << 16);
}

// ---------------- CSR build (by dst) ----------------
__global__ void count_dst_kernel(const int* __restrict__ dst, int* __restrict__ counts, int E) {
    int e = blockIdx.x * blockDim.x + threadIdx.x;
    if (e < E) atomicAdd(&counts[dst[e]], 1);
}

// exclusive scan of counts[n] -> offs[n], offs[n]=total. Single block, 256 threads.
__global__ void scan_kernel(const int* __restrict__ counts, int* __restrict__ offs, int n, int total) {
    __shared__ int wsum[4];
    __shared__ int carrySh;
    if (threadIdx.x == 0) carrySh = 0;
    __syncthreads();
    const int lane = threadIdx.x & 63;
    const int wv = threadIdx.x >> 6;
    for (int base = 0; base < n; base += 1024) {
        int i0 = base + (int)threadIdx.x * 4;
        int v0 = (i0 + 0 < n) ? counts[i0 + 0] : 0;
        int v1 = (i0 + 1 < n) ? counts[i0 + 1] : 0;
        int v2 = (i0 + 2 < n) ? counts[i0 + 2] : 0;
        int v3 = (i0 + 3 < n) ? counts[i0 + 3] : 0;
        int s4 = v0 + v1 + v2 + v3;
        int s = s4;
        #pragma unroll
        for (int off = 1; off < 64; off <<= 1) {
            int t = __shfl_up(s, off, 64);
            if (lane >= off) s += t;
        }
        if (lane == 63) wsum[wv] = s;
        __syncthreads();
        int carry = carrySh;
        int wpre = 0;
        for (int w = 0; w < wv; ++w) wpre += wsum[w];
        int excl = carry + wpre + s - s4;
        if (i0 + 0 < n) offs[i0 + 0] = excl;
        excl += v0;
        if (i0 + 1 < n) offs[i0 + 1] = excl;
        excl += v1;
        if (i0 + 2 < n) offs[i0 + 2] = excl;
        excl += v2;
        if (i0 + 3 < n) offs[i0 + 3] = excl;
        __syncthreads();
        if (threadIdx.x == 255) carrySh = carry + wpre + s;
        __syncthreads();
    }
    if (threadIdx.x == 0) offs[n] = total;
}

__global__ void scatter_kernel(const int* __restrict__ src, const int* __restrict__ dst,
                               const int* __restrict__ offs, int* __restrict__ cursor,
                               int* __restrict__ esrc, int E) {
    int e = blockIdx.x * blockDim.x + threadIdx.x;
    if (e < E) {
        int d = dst[e];
        int pos = offs[d] + atomicAdd(&cursor[d], 1);
        esrc[pos] = src[e];
    }
}

// ---------------- dual GEMM: out[:,0:NCH]=X@Wl+bl ; out[:,NCH:2NCH]=X@Wr+br, bf16 out ----------------
template <int K, int NCH>
__global__ __launch_bounds__(256) void dual_gemm_kernel(
    const float* __restrict__ X,
    const float* __restrict__ Wl, const float* __restrict__ bl,
    const float* __restrict__ Wr, const float* __restrict__ br,
    unsigned short* __restrict__ out, int N) {
    constexpr int ST = 2 * NCH;
    const int colBase = blockIdx.y * 64;
    const float* W = (colBase < NCH) ? Wl : Wr;
    const float* bias = (colBase < NCH) ? bl : br;
    const int wcol = (colBase < NCH) ? colBase : colBase - NCH;
    const int rowBase = blockIdx.x * 64;

    __shared__ float xs[32][68];  // [k][row]
    __shared__ float wsh[32][68]; // [k][col]

    const int tid = threadIdx.x;
    const int tc = tid & 15;
    const int tr = tid >> 4;
    float acc[4][4] = {};

    for (int k0 = 0; k0 < K; k0 += 32) {
        {
            int r = tid >> 3;
            int kq = (tid & 7) * 4;
            #pragma unroll
            for (int rp = 0; rp < 64; rp += 32) {
                int gr = rowBase + rp + r;
                float4 v = make_float4(0.f, 0.f, 0.f, 0.f);
                if (gr < N) v = *reinterpret_cast<const float4*>(&X[(size_t)gr * K + k0 + kq]);
                xs[kq + 0][rp + r] = v.x;
                xs[kq + 1][rp + r] = v.y;
                xs[kq + 2][rp + r] = v.z;
                xs[kq + 3][rp + r] = v.w;
            }
        }
        {
            int k = tid >> 4;
            int c4 = (tid & 15) * 4;
            #pragma unroll
            for (int kp = 0; kp < 32; kp += 16) {
                float4 wv = *reinterpret_cast<const float4*>(&W[(size_t)(k0 + kp + k) * NCH + wcol + c4]);
                wsh[kp + k][c4 + 0] = wv.x;
                wsh[kp + k][c4 + 1] = wv.y;
                wsh[kp + k][c4 + 2] = wv.z;
                wsh[kp + k][c4 + 3] = wv.w;
            }
        }
        __syncthreads();
        #pragma unroll
        for (int k = 0; k < 32; ++k) {
            float4 av = *reinterpret_cast<const float4*>(&xs[k][tr * 4]);
            float4 bv = *reinterpret_cast<const float4*>(&wsh[k][tc * 4]);
            float a[4] = {av.x, av.y, av.z, av.w};
            float b[4] = {bv.x, bv.y, bv.z, bv.w};
            #pragma unroll
            for (int i = 0; i < 4; ++i)
                #pragma unroll
                for (int j = 0; j < 4; ++j) acc[i][j] += a[i] * b[j];
        }
        __syncthreads();
    }
    #pragma unroll
    for (int i = 0; i < 4; ++i) {
        int gr = rowBase + tr * 4 + i;
        if (gr < N) {
            ushort4 o;
            o.x = f2bf(acc[i][0] + bias[wcol + tc * 4 + 0]);
            o.y = f2bf(acc[i][1] + bias[wcol + tc * 4 + 1]);
            o.z = f2bf(acc[i][2] + bias[wcol + tc * 4 + 2]);
            o.w = f2bf(acc[i][3] + bias[wcol + tc * 4 + 3]);
            *reinterpret_cast<ushort4*>(&out[(size_t)gr * ST + colBase + tc * 4]) = o;
        }
    }
}

// ---------------- GATv2 aggregation: one wave per dst node, U-way edge ILP ----------------
// proj row layout (bf16): [xl (H*64) | xr (H*64)]. exp without max-sub (logits O(1)).
template <int H, int U>
__global__ __launch_bounds__(256) void gat_agg_kernel(
    const unsigned short* __restrict__ proj,
    const int* __restrict__ offs, const int* __restrict__ esrc,
    const float* __restrict__ att,   // [H,64]
    const float* __restrict__ bias,  // [H*64]
    float* __restrict__ outh,        // [N, H*64] (relu applied)
    int N) {
    constexpr int C = 64;
    constexpr int HC = H * C;
    constexpr int ST = 2 * HC;
    const int lane = threadIdx.x & 63;
    const int node = blockIdx.x * 4 + (threadIdx.x >> 6);
    if (node >= N) return;

    float xr[H], attv[H], acc[H], den[H];
    {
        const unsigned short* prow = proj + (size_t)node * ST + HC;
        #pragma unroll
        for (int h = 0; h < H; ++h) {
            xr[h] = bf2f(prow[h * C + lane]);
            attv[h] = att[h * C + lane];
            acc[h] = 0.f;
            den[h] = 0.f;
        }
    }
    // self loop (always present)
    {
        const unsigned short* pl = proj + (size_t)node * ST;
        float xl[H], s[H];
        #pragma unroll
        for (int h = 0; h < H; ++h) {
            xl[h] = bf2f(pl[h * C + lane]);
            float t = xl[h] + xr[h];
            t = (t > 0.f) ? t : LRELU_SLOPE * t;
            s[h] = t * attv[h];
        }
        #pragma unroll
        for (int off = 32; off > 0; off >>= 1)
            #pragma unroll
            for (int h = 0; h < H; ++h) s[h] += __shfl_xor(s[h], off, 64);
        #pragma unroll
        for (int h = 0; h < H; ++h) {
            float p = __expf(s[h]);
            den[h] += p;
            acc[h] += p * xl[h];
        }
    }
    const int beg = offs[node];
    const int end = offs[node + 1];
    for (int i = beg; i < end; i += U) {
        const int nv = end - i;  // valid this iter: min(nv, U)
        int src[U];
        #pragma unroll
        for (int j = 0; j < U; ++j) {
            int idx = i + j;
            idx = (idx < end) ? idx : (end - 1);  // clamp: stays in-bounds
            src[j] = esrc[idx];
        }
        float xl[U][H], s[U][H];
        #pragma unroll
        for (int j = 0; j < U; ++j) {
            const unsigned short* pl = proj + (size_t)src[j] * ST;
            #pragma unroll
            for (int h = 0; h < H; ++h) xl[j][h] = bf2f(pl[h * C + lane]);
        }
        #pragma unroll
        for (int j = 0; j < U; ++j)
            #pragma unroll
            for (int h = 0; h < H; ++h) {
                float t = xl[j][h] + xr[h];
                t = (t > 0.f) ? t : LRELU_SLOPE * t;
                s[j][h] = t * attv[h];
            }
        #pragma unroll
        for (int off = 32; off > 0; off >>= 1)
            #pragma unroll
            for (int j = 0; j < U; ++j)
                #pragma unroll
                for (int h = 0; h < H; ++h) s[j][h] += __shfl_xor(s[j][h], off, 64);
        #pragma unroll
        for (int j = 0; j < U; ++j) {
            const float w = (j < nv) ? 1.f : 0.f;
            #pragma unroll
            for (int h = 0; h < H; ++h) {
                float p = w * __expf(s[j][h]);
                den[h] += p;
                acc[h] += p * xl[j][h];
            }
        }
    }
    #pragma unroll
    for (int h = 0; h < H; ++h) {
        float v = acc[h] / den[h] + bias[h * C + lane];
        outh[(size_t)node * HC + h * C + lane] = (v > 0.f) ? v : 0.f;
    }
}

// ---------------- BatchNorm over nodes ----------------
template <int CH>
__global__ void bn_stats_kernel(const float* __restrict__ h, float* __restrict__ stats, int N) {
    const int c = threadIdx.x;
    float s = 0.f, q = 0.f;
    for (int r = blockIdx.x; r < N; r += gridDim.x) {
        float v = h[(size_t)r * CH + c];
        s += v;
        q += v * v;
    }
    atomicAdd(&stats[c], s);
    atomicAdd(&stats[CH + c], q);
}

template <int CH>
__global__ void bn_finalize_kernel(const float* __restrict__ stats,
                                   const float* __restrict__ gamma, const float* __restrict__ beta,
                                   float* __restrict__ ss, int N) {
    int c = threadIdx.x;
    float mu = stats[c] / (float)N;
    float var = stats[CH + c] / (float)N - mu * mu;
    float sc = gamma[c] * rsqrtf(var + BN_EPS);
    ss[c] = sc;
    ss[CH + c] = beta[c] - mu * sc;
}

template <int CH>
__global__ void bn_apply4_kernel(float* __restrict__ h, const float* __restrict__ ss, size_t total4) {
    size_t i = (size_t)blockIdx.x * blockDim.x + threadIdx.x;
    if (i >= total4) return;
    size_t e = i * 4;
    int c = (int)(e % CH);
    float4 v = *reinterpret_cast<float4*>(&h[e]);
    v.x = v.x * ss[c + 0] + ss[CH + c + 0];
    v.y = v.y * ss[c + 1] + ss[CH + c + 1];
    v.z = v.z * ss[c + 2] + ss[CH + c + 2];
    v.w = v.w * ss[c + 3] + ss[CH + c + 3];
    *reinterpret_cast<float4*>(&h[e]) = v;
}

extern "C" void kernel_launch(void* const* d_in, const int* in_sizes, int n_in,
                              void* d_out, int out_size, void* d_ws, size_t ws_size,
                              hipStream_t stream) {
    const float* x     = (const float*)d_in[0];
    const int*   eidx  = (const int*)d_in[1];
    const float* Wl0   = (const float*)d_in[2];
    const float* bl0   = (const float*)d_in[3];
    const float* Wr0   = (const float*)d_in[4];
    const float* br0   = (const float*)d_in[5];
    const float* att0  = (const float*)d_in[6];
    const float* bias0 = (const float*)d_in[7];
    const float* g0    = (const float*)d_in[8];
    const float* be0   = (const float*)d_in[9];
    const float* Wl1   = (const float*)d_in[10];
    const float* bl1   = (const float*)d_in[11];
    const float* Wr1   = (const float*)d_in[12];
    const float* br1   = (const float*)d_in[13];
    const float* att1  = (const float*)d_in[14];
    const float* bias1 = (const float*)d_in[15];
    const float* g1    = (const float*)d_in[16];
    const float* be1   = (const float*)d_in[17];

    const int N = in_sizes[0] / 128;
    const int E = in_sizes[1] / 2;
    const int* srcIdx = eidx;
    const int* dstIdx = eidx + E;

    char* base = (char*)d_ws;
    auto alloc = [&](size_t bytes) {
        char* p = base;
        base += (bytes + 255) & ~(size_t)255;
        return p;
    };
    unsigned short* proj = (unsigned short*)alloc((size_t)N * 384 * 2);  // bf16 [xl|xr]; reused layer1
    float* h0    = (float*)alloc((size_t)N * 192 * 4);
    int*   offs  = (int*)alloc((size_t)(N + 1) * 4);
    int*   cursor= (int*)alloc((size_t)N * 4);
    int*   esrc  = (int*)alloc((size_t)E * 4);
    float* stats = (float*)alloc(384 * 4);
    float* ss    = (float*)alloc(384 * 4);

    // ---- CSR by dst ----
    hipMemsetAsync(cursor, 0, (size_t)N * 4, stream);
    count_dst_kernel<<<(E + 255) / 256, 256, 0, stream>>>(dstIdx, cursor, E);
    scan_kernel<<<1, 256, 0, stream>>>(cursor, offs, N, E);
    hipMemsetAsync(cursor, 0, (size_t)N * 4, stream);
    scatter_kernel<<<(E + 255) / 256, 256, 0, stream>>>(srcIdx, dstIdx, offs, cursor, esrc, E);

    // ---- layer 0: 128 -> 3x64 (concat 192) ----
    {
        dim3 grid((N + 63) / 64, 6);
        dual_gemm_kernel<128, 192><<<grid, 256, 0, stream>>>(x, Wl0, bl0, Wr0, br0, proj, N);
    }
    gat_agg_kernel<3, 4><<<(N + 3) / 4, 256, 0, stream>>>(proj, offs, esrc, att0, bias0, h0, N);
    hipMemsetAsync(stats, 0, 384 * 4, stream);
    bn_stats_kernel<192><<<256, 192, 0, stream>>>(h0, stats, N);
    bn_finalize_kernel<192><<<1, 192, 0, stream>>>(stats, g0, be0, ss, N);
    {
        size_t tot4 = (size_t)N * 192 / 4;
        bn_apply4_kernel<192><<<(unsigned)((tot4 + 255) / 256), 256, 0, stream>>>(h0, ss, tot4);
    }

    // ---- layer 1: 192 -> 1x64 ----
    {
        dim3 grid((N + 63) / 64, 2);
        dual_gemm_kernel<192, 64><<<grid, 256, 0, stream>>>(h0, Wl1, bl1, Wr1, br1, proj, N);
    }
    float* out = (float*)d_out;
    gat_agg_kernel<1, 8><<<(N + 3) / 4, 256, 0, stream>>>(proj, offs, esrc, att1, bias1, out, N);
    hipMemsetAsync(stats, 0, 384 * 4, stream);
    bn_stats_kernel<64><<<256, 64, 0, stream>>>(out, stats, N);
    bn_finalize_kernel<64><<<1, 64, 0, stream>>>(stats, g1, be1, ss, N);
    {
        size_t tot4 = (size_t)N * 64 / 4;
        bn_apply4_kernel<64><<<(unsigned)((tot4 + 255) / 256), 256, 0, stream>>>(out, ss, tot4);
    }
}

// Round 3
// 500.343 us; speedup vs baseline: 1.2968x; 1.2358x over previous
//
#include <hip/hip_runtime.h>
#include <hip/hip_bf16.h>

#define LRELU_SLOPE 0.2f
#define BN_EPS 1e-5f

static __device__ __forceinline__ unsigned short f2bf(float f) {
    __hip_bfloat16 b = __float2bfloat16(f);
    return *reinterpret_cast<unsigned short*>(&b);
}
static __device__ __forceinline__ float bf2f(unsigned short u) {
    return __uint_as_float(((unsigned)u) << 16);
}

// ---------------- CSR build (by dst) ----------------
__global__ void count_dst_kernel(const int* __restrict__ dst, int* __restrict__ counts, int E) {
    int e = blockIdx.x * blockDim.x + threadIdx.x;
    if (e < E) atomicAdd(&counts[dst[e]], 1);
}

// exclusive scan of counts[n] -> offs[n], offs[n]=total. Single block, 256 threads.
__global__ void scan_kernel(const int* __restrict__ counts, int* __restrict__ offs, int n, int total) {
    __shared__ int wsum[4];
    __shared__ int carrySh;
    if (threadIdx.x == 0) carrySh = 0;
    __syncthreads();
    const int lane = threadIdx.x & 63;
    const int wv = threadIdx.x >> 6;
    for (int base = 0; base < n; base += 1024) {
        int i0 = base + (int)threadIdx.x * 4;
        int v0 = (i0 + 0 < n) ? counts[i0 + 0] : 0;
        int v1 = (i0 + 1 < n) ? counts[i0 + 1] : 0;
        int v2 = (i0 + 2 < n) ? counts[i0 + 2] : 0;
        int v3 = (i0 + 3 < n) ? counts[i0 + 3] : 0;
        int s4 = v0 + v1 + v2 + v3;
        int s = s4;
        #pragma unroll
        for (int off = 1; off < 64; off <<= 1) {
            int t = __shfl_up(s, off, 64);
            if (lane >= off) s += t;
        }
        if (lane == 63) wsum[wv] = s;
        __syncthreads();
        int carry = carrySh;
        int wpre = 0;
        for (int w = 0; w < wv; ++w) wpre += wsum[w];
        int excl = carry + wpre + s - s4;
        if (i0 + 0 < n) offs[i0 + 0] = excl;
        excl += v0;
        if (i0 + 1 < n) offs[i0 + 1] = excl;
        excl += v1;
        if (i0 + 2 < n) offs[i0 + 2] = excl;
        excl += v2;
        if (i0 + 3 < n) offs[i0 + 3] = excl;
        __syncthreads();
        if (threadIdx.x == 255) carrySh = carry + wpre + s;
        __syncthreads();
    }
    if (threadIdx.x == 0) offs[n] = total;
}

__global__ void scatter_kernel(const int* __restrict__ src, const int* __restrict__ dst,
                               const int* __restrict__ offs, int* __restrict__ cursor,
                               int* __restrict__ esrc, int E) {
    int e = blockIdx.x * blockDim.x + threadIdx.x;
    if (e < E) {
        int d = dst[e];
        int pos = offs[d] + atomicAdd(&cursor[d], 1);
        esrc[pos] = src[e];
    }
}

// ---------------- dual GEMM: out[:,0:NCH]=X@Wl+bl ; out[:,NCH:2NCH]=X@Wr+br, bf16 out ----------------
template <int K, int NCH>
__global__ __launch_bounds__(256) void dual_gemm_kernel(
    const float* __restrict__ X,
    const float* __restrict__ Wl, const float* __restrict__ bl,
    const float* __restrict__ Wr, const float* __restrict__ br,
    unsigned short* __restrict__ out, int N) {
    constexpr int ST = 2 * NCH;
    const int colBase = blockIdx.y * 64;
    const float* W = (colBase < NCH) ? Wl : Wr;
    const float* bias = (colBase < NCH) ? bl : br;
    const int wcol = (colBase < NCH) ? colBase : colBase - NCH;
    const int rowBase = blockIdx.x * 64;

    __shared__ float xs[32][68];  // [k][row]
    __shared__ float wsh[32][68]; // [k][col]

    const int tid = threadIdx.x;
    const int tc = tid & 15;
    const int tr = tid >> 4;
    float acc[4][4] = {};

    for (int k0 = 0; k0 < K; k0 += 32) {
        {
            int r = tid >> 3;
            int kq = (tid & 7) * 4;
            #pragma unroll
            for (int rp = 0; rp < 64; rp += 32) {
                int gr = rowBase + rp + r;
                float4 v = make_float4(0.f, 0.f, 0.f, 0.f);
                if (gr < N) v = *reinterpret_cast<const float4*>(&X[(size_t)gr * K + k0 + kq]);
                xs[kq + 0][rp + r] = v.x;
                xs[kq + 1][rp + r] = v.y;
                xs[kq + 2][rp + r] = v.z;
                xs[kq + 3][rp + r] = v.w;
            }
        }
        {
            int k = tid >> 4;
            int c4 = (tid & 15) * 4;
            #pragma unroll
            for (int kp = 0; kp < 32; kp += 16) {
                float4 wv = *reinterpret_cast<const float4*>(&W[(size_t)(k0 + kp + k) * NCH + wcol + c4]);
                wsh[kp + k][c4 + 0] = wv.x;
                wsh[kp + k][c4 + 1] = wv.y;
                wsh[kp + k][c4 + 2] = wv.z;
                wsh[kp + k][c4 + 3] = wv.w;
            }
        }
        __syncthreads();
        #pragma unroll
        for (int k = 0; k < 32; ++k) {
            float4 av = *reinterpret_cast<const float4*>(&xs[k][tr * 4]);
            float4 bv = *reinterpret_cast<const float4*>(&wsh[k][tc * 4]);
            float a[4] = {av.x, av.y, av.z, av.w};
            float b[4] = {bv.x, bv.y, bv.z, bv.w};
            #pragma unroll
            for (int i = 0; i < 4; ++i)
                #pragma unroll
                for (int j = 0; j < 4; ++j) acc[i][j] += a[i] * b[j];
        }
        __syncthreads();
    }
    #pragma unroll
    for (int i = 0; i < 4; ++i) {
        int gr = rowBase + tr * 4 + i;
        if (gr < N) {
            ushort4 o;
            o.x = f2bf(acc[i][0] + bias[wcol + tc * 4 + 0]);
            o.y = f2bf(acc[i][1] + bias[wcol + tc * 4 + 1]);
            o.z = f2bf(acc[i][2] + bias[wcol + tc * 4 + 2]);
            o.w = f2bf(acc[i][3] + bias[wcol + tc * 4 + 3]);
            *reinterpret_cast<ushort4*>(&out[(size_t)gr * ST + colBase + tc * 4]) = o;
        }
    }
}

// ---------------- GATv2 aggregation: one wave per dst node ----------------
// Lane decomposition: edge slot j = lane>>4 (4 edges in flight), channel group
// cg = 4*(lane&15) (4 channels per lane, ushort4 gathers). Per-edge logit
// reduce = 4-step shfl_xor over 16 lanes (offsets 1,2,4,8 — intra-32).
// alpha*xl accumulates lane-locally; one final (16,32) reduce per node.
// exp without max-sub (logits O(1): identical alpha, no overflow risk).
template <int H>
__global__ __launch_bounds__(256) void gat_agg_kernel(
    const unsigned short* __restrict__ proj,  // [N, 2*H*64] bf16: [xl | xr]
    const int* __restrict__ offs, const int* __restrict__ esrc,
    const float* __restrict__ att,   // [H,64]
    const float* __restrict__ bias,  // [H*64]
    float* __restrict__ outh,        // [N, H*64] (relu applied)
    int N) {
    constexpr int C = 64;
    constexpr int HC = H * C;
    constexpr int ST = 2 * HC;
    const int lane = threadIdx.x & 63;
    const int node = blockIdx.x * 4 + (threadIdx.x >> 6);
    if (node >= N) return;
    const int j = lane >> 4;          // edge slot 0..3
    const int cg = (lane & 15) * 4;   // channel base within head

    float4 xr4[H], att4[H], acc4[H];
    float den[H];
    #pragma unroll
    for (int h = 0; h < H; ++h) {
        ushort4 u = *reinterpret_cast<const ushort4*>(&proj[(size_t)node * ST + HC + h * C + cg]);
        xr4[h] = make_float4(bf2f(u.x), bf2f(u.y), bf2f(u.z), bf2f(u.w));
        att4[h] = *reinterpret_cast<const float4*>(&att[h * C + cg]);
        acc4[h] = make_float4(0.f, 0.f, 0.f, 0.f);
        den[h] = 0.f;
    }

    const int beg = offs[node];
    const int total = offs[node + 1] - beg + 1;  // virtual index 0 = self loop
    for (int t = 0; t < total; t += 4) {
        const int v = t + j;
        const float w = (v < total) ? 1.f : 0.f;
        const int vc = (v < total) ? v : (total - 1);
        const int src = (vc == 0) ? node : esrc[beg + vc - 1];

        float4 xl4[H];
        float s[H];
        #pragma unroll
        for (int h = 0; h < H; ++h) {
            ushort4 u = *reinterpret_cast<const ushort4*>(&proj[(size_t)src * ST + h * C + cg]);
            xl4[h] = make_float4(bf2f(u.x), bf2f(u.y), bf2f(u.z), bf2f(u.w));
        }
        #pragma unroll
        for (int h = 0; h < H; ++h) {
            float a0 = xl4[h].x + xr4[h].x;
            float a1 = xl4[h].y + xr4[h].y;
            float a2 = xl4[h].z + xr4[h].z;
            float a3 = xl4[h].w + xr4[h].w;
            a0 = (a0 > 0.f) ? a0 : LRELU_SLOPE * a0;
            a1 = (a1 > 0.f) ? a1 : LRELU_SLOPE * a1;
            a2 = (a2 > 0.f) ? a2 : LRELU_SLOPE * a2;
            a3 = (a3 > 0.f) ? a3 : LRELU_SLOPE * a3;
            s[h] = a0 * att4[h].x + a1 * att4[h].y + a2 * att4[h].z + a3 * att4[h].w;
        }
        #pragma unroll
        for (int off = 1; off <= 8; off <<= 1)
            #pragma unroll
            for (int h = 0; h < H; ++h) s[h] += __shfl_xor(s[h], off, 64);
        #pragma unroll
        for (int h = 0; h < H; ++h) {
            float p = w * __expf(s[h]);
            den[h] += p;
            acc4[h].x += p * xl4[h].x;
            acc4[h].y += p * xl4[h].y;
            acc4[h].z += p * xl4[h].z;
            acc4[h].w += p * xl4[h].w;
        }
    }

    // final reduce across the 4 edge-slot groups (lanes l, l^16, l^32, l^48)
    #pragma unroll
    for (int off = 16; off <= 32; off <<= 1) {
        #pragma unroll
        for (int h = 0; h < H; ++h) {
            acc4[h].x += __shfl_xor(acc4[h].x, off, 64);
            acc4[h].y += __shfl_xor(acc4[h].y, off, 64);
            acc4[h].z += __shfl_xor(acc4[h].z, off, 64);
            acc4[h].w += __shfl_xor(acc4[h].w, off, 64);
            den[h]    += __shfl_xor(den[h],    off, 64);
        }
    }

    if (j == 0) {  // lanes 0..15 hold/write all channels
        #pragma unroll
        for (int h = 0; h < H; ++h) {
            float4 b4 = *reinterpret_cast<const float4*>(&bias[h * C + cg]);
            float inv = 1.f / den[h];
            float4 o;
            o.x = acc4[h].x * inv + b4.x;
            o.y = acc4[h].y * inv + b4.y;
            o.z = acc4[h].z * inv + b4.z;
            o.w = acc4[h].w * inv + b4.w;
            o.x = (o.x > 0.f) ? o.x : 0.f;
            o.y = (o.y > 0.f) ? o.y : 0.f;
            o.z = (o.z > 0.f) ? o.z : 0.f;
            o.w = (o.w > 0.f) ? o.w : 0.f;
            *reinterpret_cast<float4*>(&outh[(size_t)node * HC + h * C + cg]) = o;
        }
    }
}

// ---------------- BatchNorm over nodes ----------------
template <int CH>
__global__ void bn_stats_kernel(const float* __restrict__ h, float* __restrict__ stats, int N) {
    const int c = threadIdx.x;
    float s = 0.f, q = 0.f;
    for (int r = blockIdx.x; r < N; r += gridDim.x) {
        float v = h[(size_t)r * CH + c];
        s += v;
        q += v * v;
    }
    atomicAdd(&stats[c], s);
    atomicAdd(&stats[CH + c], q);
}

template <int CH>
__global__ void bn_finalize_kernel(const float* __restrict__ stats,
                                   const float* __restrict__ gamma, const float* __restrict__ beta,
                                   float* __restrict__ ss, int N) {
    int c = threadIdx.x;
    float mu = stats[c] / (float)N;
    float var = stats[CH + c] / (float)N - mu * mu;
    float sc = gamma[c] * rsqrtf(var + BN_EPS);
    ss[c] = sc;
    ss[CH + c] = beta[c] - mu * sc;
}

template <int CH>
__global__ void bn_apply4_kernel(float* __restrict__ h, const float* __restrict__ ss, size_t total4) {
    size_t i = (size_t)blockIdx.x * blockDim.x + threadIdx.x;
    if (i >= total4) return;
    size_t e = i * 4;
    int c = (int)(e % CH);
    float4 v = *reinterpret_cast<float4*>(&h[e]);
    v.x = v.x * ss[c + 0] + ss[CH + c + 0];
    v.y = v.y * ss[c + 1] + ss[CH + c + 1];
    v.z = v.z * ss[c + 2] + ss[CH + c + 2];
    v.w = v.w * ss[c + 3] + ss[CH + c + 3];
    *reinterpret_cast<float4*>(&h[e]) = v;
}

extern "C" void kernel_launch(void* const* d_in, const int* in_sizes, int n_in,
                              void* d_out, int out_size, void* d_ws, size_t ws_size,
                              hipStream_t stream) {
    const float* x     = (const float*)d_in[0];
    const int*   eidx  = (const int*)d_in[1];
    const float* Wl0   = (const float*)d_in[2];
    const float* bl0   = (const float*)d_in[3];
    const float* Wr0   = (const float*)d_in[4];
    const float* br0   = (const float*)d_in[5];
    const float* att0  = (const float*)d_in[6];
    const float* bias0 = (const float*)d_in[7];
    const float* g0    = (const float*)d_in[8];
    const float* be0   = (const float*)d_in[9];
    const float* Wl1   = (const float*)d_in[10];
    const float* bl1   = (const float*)d_in[11];
    const float* Wr1   = (const float*)d_in[12];
    const float* br1   = (const float*)d_in[13];
    const float* att1  = (const float*)d_in[14];
    const float* bias1 = (const float*)d_in[15];
    const float* g1    = (const float*)d_in[16];
    const float* be1   = (const float*)d_in[17];

    const int N = in_sizes[0] / 128;
    const int E = in_sizes[1] / 2;
    const int* srcIdx = eidx;
    const int* dstIdx = eidx + E;

    char* base = (char*)d_ws;
    auto alloc = [&](size_t bytes) {
        char* p = base;
        base += (bytes + 255) & ~(size_t)255;
        return p;
    };
    unsigned short* proj = (unsigned short*)alloc((size_t)N * 384 * 2);  // bf16 [xl|xr]; reused layer1
    float* h0    = (float*)alloc((size_t)N * 192 * 4);
    int*   offs  = (int*)alloc((size_t)(N + 1) * 4);
    int*   cursor= (int*)alloc((size_t)N * 4);
    int*   esrc  = (int*)alloc((size_t)E * 4);
    float* stats = (float*)alloc(384 * 4);
    float* ss    = (float*)alloc(384 * 4);

    // ---- CSR by dst ----
    hipMemsetAsync(cursor, 0, (size_t)N * 4, stream);
    count_dst_kernel<<<(E + 255) / 256, 256, 0, stream>>>(dstIdx, cursor, E);
    scan_kernel<<<1, 256, 0, stream>>>(cursor, offs, N, E);
    hipMemsetAsync(cursor, 0, (size_t)N * 4, stream);
    scatter_kernel<<<(E + 255) / 256, 256, 0, stream>>>(srcIdx, dstIdx, offs, cursor, esrc, E);

    // ---- layer 0: 128 -> 3x64 (concat 192) ----
    {
        dim3 grid((N + 63) / 64, 6);
        dual_gemm_kernel<128, 192><<<grid, 256, 0, stream>>>(x, Wl0, bl0, Wr0, br0, proj, N);
    }
    gat_agg_kernel<3><<<(N + 3) / 4, 256, 0, stream>>>(proj, offs, esrc, att0, bias0, h0, N);
    hipMemsetAsync(stats, 0, 384 * 4, stream);
    bn_stats_kernel<192><<<256, 192, 0, stream>>>(h0, stats, N);
    bn_finalize_kernel<192><<<1, 192, 0, stream>>>(stats, g0, be0, ss, N);
    {
        size_t tot4 = (size_t)N * 192 / 4;
        bn_apply4_kernel<192><<<(unsigned)((tot4 + 255) / 256), 256, 0, stream>>>(h0, ss, tot4);
    }

    // ---- layer 1: 192 -> 1x64 ----
    {
        dim3 grid((N + 63) / 64, 2);
        dual_gemm_kernel<192, 64><<<grid, 256, 0, stream>>>(h0, Wl1, bl1, Wr1, br1, proj, N);
    }
    float* out = (float*)d_out;
    gat_agg_kernel<1><<<(N + 3) / 4, 256, 0, stream>>>(proj, offs, esrc, att1, bias1, out, N);
    hipMemsetAsync(stats, 0, 384 * 4, stream);
    bn_stats_kernel<64><<<256, 64, 0, stream>>>(out, stats, N);
    bn_finalize_kernel<64><<<1, 64, 0, stream>>>(stats, g1, be1, ss, N);
    {
        size_t tot4 = (size_t)N * 64 / 4;
        bn_apply4_kernel<64><<<(unsigned)((tot4 + 255) / 256), 256, 0, stream>>>(out, ss, tot4);
    }
}

// Round 4
// 408.888 us; speedup vs baseline: 1.5869x; 1.2237x over previous
//
#include <hip/hip_runtime.h>
#include <hip/hip_bf16.h>

#define LRELU_SLOPE 0.2f
#define BN_EPS 1e-5f

typedef __attribute__((ext_vector_type(8))) short short8v;
typedef __attribute__((ext_vector_type(4))) float float4v;

static __device__ __forceinline__ unsigned short f2bf(float f) {
    __hip_bfloat16 b = __float2bfloat16(f);
    return *reinterpret_cast<unsigned short*>(&b);
}
static __device__ __forceinline__ float bf2f(unsigned short u) {
    return __uint_as_float(((unsigned)u) << 16);
}

// ---------------- weight pre-convert: Wt[c][k] bf16 = W{l,r}[k][c] ----------------
__global__ void convert_w_kernel(const float* __restrict__ Wl, const float* __restrict__ Wr,
                                 unsigned short* __restrict__ Wt, int K, int NCH) {
    int idx = blockIdx.x * blockDim.x + threadIdx.x;
    int total = 2 * NCH * K;
    if (idx >= total) return;
    int c = idx / K;
    int k = idx % K;
    float v = (c < NCH) ? Wl[(size_t)k * NCH + c] : Wr[(size_t)k * NCH + (c - NCH)];
    Wt[idx] = f2bf(v);
}

// ---------------- CSR build (by dst) ----------------
__global__ void count_dst_kernel(const int* __restrict__ dst, int* __restrict__ counts, int E) {
    int e = blockIdx.x * blockDim.x + threadIdx.x;
    if (e < E) atomicAdd(&counts[dst[e]], 1);
}

// phase A: per-1024-chunk local exclusive scan; blkSum[b] = chunk total
__global__ void scanA_kernel(const int* __restrict__ counts, int* __restrict__ offs,
                             int* __restrict__ blkSum, int n) {
    __shared__ int wsum[4];
    const int lane = threadIdx.x & 63;
    const int wv = threadIdx.x >> 6;
    int i0 = blockIdx.x * 1024 + (int)threadIdx.x * 4;
    int v0 = (i0 + 0 < n) ? counts[i0 + 0] : 0;
    int v1 = (i0 + 1 < n) ? counts[i0 + 1] : 0;
    int v2 = (i0 + 2 < n) ? counts[i0 + 2] : 0;
    int v3 = (i0 + 3 < n) ? counts[i0 + 3] : 0;
    int s4 = v0 + v1 + v2 + v3;
    int s = s4;
    #pragma unroll
    for (int off = 1; off < 64; off <<= 1) {
        int t = __shfl_up(s, off, 64);
        if (lane >= off) s += t;
    }
    if (lane == 63) wsum[wv] = s;
    __syncthreads();
    int wpre = 0;
    for (int w = 0; w < wv; ++w) wpre += wsum[w];
    int excl = wpre + s - s4;
    if (i0 + 0 < n) offs[i0 + 0] = excl;
    excl += v0;
    if (i0 + 1 < n) offs[i0 + 1] = excl;
    excl += v1;
    if (i0 + 2 < n) offs[i0 + 2] = excl;
    excl += v2;
    if (i0 + 3 < n) offs[i0 + 3] = excl;
    if (threadIdx.x == 255) blkSum[blockIdx.x] = wpre + s;
}

// phase B: single wave exclusive scan of blkSum[nb] (nb <= 64)
__global__ void scanB_kernel(const int* __restrict__ blkSum, int* __restrict__ blkOff, int nb) {
    int l = threadIdx.x;
    int v = (l < nb) ? blkSum[l] : 0;
    int s = v;
    #pragma unroll
    for (int off = 1; off < 64; off <<= 1) {
        int t = __shfl_up(s, off, 64);
        if (l >= off) s += t;
    }
    if (l < nb) blkOff[l] = s - v;
}

// phase C: add chunk offsets; write sentinel offs[n] = E
__global__ void scanC_kernel(int* __restrict__ offs, const int* __restrict__ blkOff, int n, int E) {
    int i = blockIdx.x * blockDim.x + threadIdx.x;
    if (i < n) offs[i] += blkOff[i >> 10];
    if (i == 0) offs[n] = E;
}

__global__ void scatter_kernel(const int* __restrict__ src, const int* __restrict__ dst,
                               const int* __restrict__ offs, int* __restrict__ cursor,
                               int* __restrict__ esrc, int E) {
    int e = blockIdx.x * blockDim.x + threadIdx.x;
    if (e < E) {
        int d = dst[e];
        int pos = offs[d] + atomicAdd(&cursor[d], 1);
        esrc[pos] = src[e];
    }
}

// ---------------- MFMA dual GEMM ----------------
// out[:,0:NCH]=X@Wl+bl ; out[:,NCH:2NCH]=X@Wr+br (bf16 out).
// Wt: [2*NCH][K] bf16 (pre-transposed). BN: apply x*ss[k]+ss[K+k] during A staging.
// Tile 128x128, 4 waves, each wave 32 rows x 128 cols via 2x8 16x16x32 frags.
// LDS stride 40 bf16 (80 B): 16B-aligned b128 reads, 2-way bank conflicts (free).
template <int K, int NCH, bool BN>
__global__ __launch_bounds__(256) void mfma_dual_gemm(
    const float* __restrict__ X,
    const unsigned short* __restrict__ Wt,
    const float* __restrict__ bl, const float* __restrict__ br,
    const float* __restrict__ ss,
    unsigned short* __restrict__ out, int N) {
    constexpr int ST = 2 * NCH;
    constexpr int LDA = 40;
    const int rowBase = blockIdx.x * 128;
    const int colBase = blockIdx.y * 128;

    __shared__ unsigned short XS[128 * LDA];
    __shared__ unsigned short WS[128 * LDA];

    const int tid = threadIdx.x;
    const int lane = tid & 63;
    const int wv = tid >> 6;
    const int lrow = lane & 15;
    const int lk = lane >> 4;

    float4v acc[2][8];
    #pragma unroll
    for (int i = 0; i < 2; ++i)
        #pragma unroll
        for (int j = 0; j < 8; ++j) acc[i][j] = (float4v){0.f, 0.f, 0.f, 0.f};

    for (int k0 = 0; k0 < K; k0 += 32) {
        // stage X (128 rows x 32 k), fp32 -> bf16, optional BN
        {
            int r = tid >> 3;
            int kq = (tid & 7) * 4;
            float4 sc0, sc1;
            if (BN) {
                sc0 = *reinterpret_cast<const float4*>(&ss[k0 + kq]);
                sc1 = *reinterpret_cast<const float4*>(&ss[K + k0 + kq]);
            }
            #pragma unroll
            for (int i = 0; i < 4; ++i) {
                int row = r + 32 * i;
                int gr = rowBase + row;
                float4 v = make_float4(0.f, 0.f, 0.f, 0.f);
                if (gr < N) v = *reinterpret_cast<const float4*>(&X[(size_t)gr * K + k0 + kq]);
                if (BN) {
                    v.x = v.x * sc0.x + sc1.x;
                    v.y = v.y * sc0.y + sc1.y;
                    v.z = v.z * sc0.z + sc1.z;
                    v.w = v.w * sc0.w + sc1.w;
                }
                ushort4 u;
                u.x = f2bf(v.x); u.y = f2bf(v.y); u.z = f2bf(v.z); u.w = f2bf(v.w);
                *reinterpret_cast<ushort4*>(&XS[row * LDA + kq]) = u;
            }
        }
        // stage W (128 cols x 32 k) bf16 direct
        {
            int c = tid >> 2;
            int kq8 = (tid & 3) * 8;
            #pragma unroll
            for (int i = 0; i < 2; ++i) {
                int col = c + 64 * i;
                uint4 w = *reinterpret_cast<const uint4*>(&Wt[(size_t)(colBase + col) * K + k0 + kq8]);
                *reinterpret_cast<uint4*>(&WS[col * LDA + kq8]) = w;
            }
        }
        __syncthreads();
        short8v aF[2], bF[8];
        #pragma unroll
        for (int rb = 0; rb < 2; ++rb)
            aF[rb] = *reinterpret_cast<const short8v*>(&XS[(wv * 32 + rb * 16 + lrow) * LDA + lk * 8]);
        #pragma unroll
        for (int cb = 0; cb < 8; ++cb)
            bF[cb] = *reinterpret_cast<const short8v*>(&WS[(cb * 16 + lrow) * LDA + lk * 8]);
        #pragma unroll
        for (int rb = 0; rb < 2; ++rb)
            #pragma unroll
            for (int cb = 0; cb < 8; ++cb)
                acc[rb][cb] = __builtin_amdgcn_mfma_f32_16x16x32_bf16(aF[rb], bF[cb], acc[rb][cb], 0, 0, 0);
        __syncthreads();
    }
    // epilogue: D row = lk*4+r (within 16-block), col = lrow
    #pragma unroll
    for (int cb = 0; cb < 8; ++cb) {
        int cg = colBase + cb * 16 + lrow;
        float bv = (cg < NCH) ? bl[cg] : br[cg - NCH];
        #pragma unroll
        for (int rb = 0; rb < 2; ++rb) {
            #pragma unroll
            for (int r = 0; r < 4; ++r) {
                int row = rowBase + wv * 32 + rb * 16 + lk * 4 + r;
                if (row < N) out[(size_t)row * ST + cg] = f2bf(acc[rb][cb][r] + bv);
            }
        }
    }
}

// ---------------- GATv2 aggregation: one wave per dst node ----------------
// edge slot j = lane>>4, channel group cg = 4*(lane&15). Per-edge logit reduce =
// 4-step shfl over 16 lanes; lane-local alpha*xl accumulate; final (16,32) reduce.
template <int H>
__global__ __launch_bounds__(256) void gat_agg_kernel(
    const unsigned short* __restrict__ proj,
    const int* __restrict__ offs, const int* __restrict__ esrc,
    const float* __restrict__ att, const float* __restrict__ bias,
    float* __restrict__ outh, int N) {
    constexpr int C = 64;
    constexpr int HC = H * C;
    constexpr int ST = 2 * HC;
    const int lane = threadIdx.x & 63;
    const int node = blockIdx.x * 4 + (threadIdx.x >> 6);
    if (node >= N) return;
    const int j = lane >> 4;
    const int cg = (lane & 15) * 4;

    float4 xr4[H], att4[H], acc4[H];
    float den[H];
    #pragma unroll
    for (int h = 0; h < H; ++h) {
        ushort4 u = *reinterpret_cast<const ushort4*>(&proj[(size_t)node * ST + HC + h * C + cg]);
        xr4[h] = make_float4(bf2f(u.x), bf2f(u.y), bf2f(u.z), bf2f(u.w));
        att4[h] = *reinterpret_cast<const float4*>(&att[h * C + cg]);
        acc4[h] = make_float4(0.f, 0.f, 0.f, 0.f);
        den[h] = 0.f;
    }

    const int beg = offs[node];
    const int total = offs[node + 1] - beg + 1;  // virtual index 0 = self loop
    for (int t = 0; t < total; t += 4) {
        const int v = t + j;
        const float w = (v < total) ? 1.f : 0.f;
        const int vc = (v < total) ? v : (total - 1);
        const int src = (vc == 0) ? node : esrc[beg + vc - 1];

        float4 xl4[H];
        float s[H];
        #pragma unroll
        for (int h = 0; h < H; ++h) {
            ushort4 u = *reinterpret_cast<const ushort4*>(&proj[(size_t)src * ST + h * C + cg]);
            xl4[h] = make_float4(bf2f(u.x), bf2f(u.y), bf2f(u.z), bf2f(u.w));
        }
        #pragma unroll
        for (int h = 0; h < H; ++h) {
            float a0 = xl4[h].x + xr4[h].x;
            float a1 = xl4[h].y + xr4[h].y;
            float a2 = xl4[h].z + xr4[h].z;
            float a3 = xl4[h].w + xr4[h].w;
            a0 = (a0 > 0.f) ? a0 : LRELU_SLOPE * a0;
            a1 = (a1 > 0.f) ? a1 : LRELU_SLOPE * a1;
            a2 = (a2 > 0.f) ? a2 : LRELU_SLOPE * a2;
            a3 = (a3 > 0.f) ? a3 : LRELU_SLOPE * a3;
            s[h] = a0 * att4[h].x + a1 * att4[h].y + a2 * att4[h].z + a3 * att4[h].w;
        }
        #pragma unroll
        for (int off = 1; off <= 8; off <<= 1)
            #pragma unroll
            for (int h = 0; h < H; ++h) s[h] += __shfl_xor(s[h], off, 64);
        #pragma unroll
        for (int h = 0; h < H; ++h) {
            float p = w * __expf(s[h]);
            den[h] += p;
            acc4[h].x += p * xl4[h].x;
            acc4[h].y += p * xl4[h].y;
            acc4[h].z += p * xl4[h].z;
            acc4[h].w += p * xl4[h].w;
        }
    }

    #pragma unroll
    for (int off = 16; off <= 32; off <<= 1) {
        #pragma unroll
        for (int h = 0; h < H; ++h) {
            acc4[h].x += __shfl_xor(acc4[h].x, off, 64);
            acc4[h].y += __shfl_xor(acc4[h].y, off, 64);
            acc4[h].z += __shfl_xor(acc4[h].z, off, 64);
            acc4[h].w += __shfl_xor(acc4[h].w, off, 64);
            den[h]    += __shfl_xor(den[h],    off, 64);
        }
    }

    if (j == 0) {
        #pragma unroll
        for (int h = 0; h < H; ++h) {
            float4 b4 = *reinterpret_cast<const float4*>(&bias[h * C + cg]);
            float inv = 1.f / den[h];
            float4 o;
            o.x = acc4[h].x * inv + b4.x;
            o.y = acc4[h].y * inv + b4.y;
            o.z = acc4[h].z * inv + b4.z;
            o.w = acc4[h].w * inv + b4.w;
            o.x = (o.x > 0.f) ? o.x : 0.f;
            o.y = (o.y > 0.f) ? o.y : 0.f;
            o.z = (o.z > 0.f) ? o.z : 0.f;
            o.w = (o.w > 0.f) ? o.w : 0.f;
            *reinterpret_cast<float4*>(&outh[(size_t)node * HC + h * C + cg]) = o;
        }
    }
}

// ---------------- BatchNorm over nodes ----------------
template <int CH>
__global__ void bn_stats_kernel(const float* __restrict__ h, float* __restrict__ stats, int N) {
    const int c = threadIdx.x;
    float s = 0.f, q = 0.f;
    for (int r = blockIdx.x; r < N; r += gridDim.x) {
        float v = h[(size_t)r * CH + c];
        s += v;
        q += v * v;
    }
    atomicAdd(&stats[c], s);
    atomicAdd(&stats[CH + c], q);
}

template <int CH>
__global__ void bn_finalize_kernel(const float* __restrict__ stats,
                                   const float* __restrict__ gamma, const float* __restrict__ beta,
                                   float* __restrict__ ss, int N) {
    int c = threadIdx.x;
    float mu = stats[c] / (float)N;
    float var = stats[CH + c] / (float)N - mu * mu;
    float sc = gamma[c] * rsqrtf(var + BN_EPS);
    ss[c] = sc;
    ss[CH + c] = beta[c] - mu * sc;
}

template <int CH>
__global__ void bn_apply4_kernel(float* __restrict__ h, const float* __restrict__ ss, size_t total4) {
    size_t i = (size_t)blockIdx.x * blockDim.x + threadIdx.x;
    if (i >= total4) return;
    size_t e = i * 4;
    int c = (int)(e % CH);
    float4 v = *reinterpret_cast<float4*>(&h[e]);
    v.x = v.x * ss[c + 0] + ss[CH + c + 0];
    v.y = v.y * ss[c + 1] + ss[CH + c + 1];
    v.z = v.z * ss[c + 2] + ss[CH + c + 2];
    v.w = v.w * ss[c + 3] + ss[CH + c + 3];
    *reinterpret_cast<float4*>(&h[e]) = v;
}

extern "C" void kernel_launch(void* const* d_in, const int* in_sizes, int n_in,
                              void* d_out, int out_size, void* d_ws, size_t ws_size,
                              hipStream_t stream) {
    const float* x     = (const float*)d_in[0];
    const int*   eidx  = (const int*)d_in[1];
    const float* Wl0   = (const float*)d_in[2];
    const float* bl0   = (const float*)d_in[3];
    const float* Wr0   = (const float*)d_in[4];
    const float* br0   = (const float*)d_in[5];
    const float* att0  = (const float*)d_in[6];
    const float* bias0 = (const float*)d_in[7];
    const float* g0    = (const float*)d_in[8];
    const float* be0   = (const float*)d_in[9];
    const float* Wl1   = (const float*)d_in[10];
    const float* bl1   = (const float*)d_in[11];
    const float* Wr1   = (const float*)d_in[12];
    const float* br1   = (const float*)d_in[13];
    const float* att1  = (const float*)d_in[14];
    const float* bias1 = (const float*)d_in[15];
    const float* g1    = (const float*)d_in[16];
    const float* be1   = (const float*)d_in[17];

    const int N = in_sizes[0] / 128;
    const int E = in_sizes[1] / 2;
    const int* srcIdx = eidx;
    const int* dstIdx = eidx + E;
    const int nChunks = (N + 1023) >> 10;

    char* base = (char*)d_ws;
    auto alloc = [&](size_t bytes) {
        char* p = base;
        base += (bytes + 255) & ~(size_t)255;
        return p;
    };
    unsigned short* proj = (unsigned short*)alloc((size_t)N * 384 * 2);
    float* h0    = (float*)alloc((size_t)N * 192 * 4);
    int*   offs  = (int*)alloc((size_t)(N + 1) * 4);
    int*   counts= (int*)alloc((size_t)N * 4);
    int*   cursor= (int*)alloc((size_t)N * 4);
    int*   esrc  = (int*)alloc((size_t)E * 4);
    int*   blkSum= (int*)alloc((size_t)nChunks * 4);
    int*   blkOff= (int*)alloc((size_t)nChunks * 4);
    float* stats = (float*)alloc(384 * 4);
    float* ss    = (float*)alloc(384 * 4);
    unsigned short* Wt0 = (unsigned short*)alloc((size_t)384 * 128 * 2);
    unsigned short* Wt1 = (unsigned short*)alloc((size_t)128 * 192 * 2);

    // ---- weight pre-convert (bf16, transposed) ----
    convert_w_kernel<<<(384 * 128 + 255) / 256, 256, 0, stream>>>(Wl0, Wr0, Wt0, 128, 192);
    convert_w_kernel<<<(128 * 192 + 255) / 256, 256, 0, stream>>>(Wl1, Wr1, Wt1, 192, 64);

    // ---- CSR by dst ----
    hipMemsetAsync(counts, 0, (size_t)N * 4, stream);
    hipMemsetAsync(cursor, 0, (size_t)N * 4, stream);
    count_dst_kernel<<<(E + 255) / 256, 256, 0, stream>>>(dstIdx, counts, E);
    scanA_kernel<<<nChunks, 256, 0, stream>>>(counts, offs, blkSum, N);
    scanB_kernel<<<1, 64, 0, stream>>>(blkSum, blkOff, nChunks);
    scanC_kernel<<<(N + 255) / 256, 256, 0, stream>>>(offs, blkOff, N, E);
    scatter_kernel<<<(E + 255) / 256, 256, 0, stream>>>(srcIdx, dstIdx, offs, cursor, esrc, E);

    // ---- layer 0: 128 -> 3x64 (concat 192) ----
    {
        dim3 grid((N + 127) / 128, 3);
        mfma_dual_gemm<128, 192, false><<<grid, 256, 0, stream>>>(x, Wt0, bl0, br0, nullptr, proj, N);
    }
    gat_agg_kernel<3><<<(N + 3) / 4, 256, 0, stream>>>(proj, offs, esrc, att0, bias0, h0, N);
    hipMemsetAsync(stats, 0, 384 * 4, stream);
    bn_stats_kernel<192><<<256, 192, 0, stream>>>(h0, stats, N);
    bn_finalize_kernel<192><<<1, 192, 0, stream>>>(stats, g0, be0, ss, N);

    // ---- layer 1: 192 -> 1x64 (BN fused into A staging) ----
    {
        dim3 grid((N + 127) / 128, 1);
        mfma_dual_gemm<192, 64, true><<<grid, 256, 0, stream>>>(h0, Wt1, bl1, br1, ss, proj, N);
    }
    float* out = (float*)d_out;
    gat_agg_kernel<1><<<(N + 3) / 4, 256, 0, stream>>>(proj, offs, esrc, att1, bias1, out, N);
    hipMemsetAsync(stats, 0, 384 * 4, stream);
    bn_stats_kernel<64><<<256, 64, 0, stream>>>(out, stats, N);
    bn_finalize_kernel<64><<<1, 64, 0, stream>>>(stats, g1, be1, ss, N);
    {
        size_t tot4 = (size_t)N * 64 / 4;
        bn_apply4_kernel<64><<<(unsigned)((tot4 + 255) / 256), 256, 0, stream>>>(out, ss, tot4);
    }
}

// Round 5
// 378.254 us; speedup vs baseline: 1.7154x; 1.0810x over previous
//
#include <hip/hip_runtime.h>
#include <hip/hip_bf16.h>

#define LRELU_SLOPE 0.2f
#define BN_EPS 1e-5f

typedef __attribute__((ext_vector_type(8))) short short8v;
typedef __attribute__((ext_vector_type(4))) float float4v;

static __device__ __forceinline__ unsigned short f2bf(float f) {
    __hip_bfloat16 b = __float2bfloat16(f);
    return *reinterpret_cast<unsigned short*>(&b);
}
static __device__ __forceinline__ float bf2f(unsigned short u) {
    return __uint_as_float(((unsigned)u) << 16);
}
static __device__ __forceinline__ void unpack2(unsigned int u, float& f0, float& f1) {
    f0 = __uint_as_float(u << 16);
    f1 = __uint_as_float(u & 0xffff0000u);
}

// ---------------- merged weight pre-convert: Wt[c][k] bf16 (both layers) ----------------
__global__ void convert_w2_kernel(const float* __restrict__ Wl0, const float* __restrict__ Wr0,
                                  const float* __restrict__ Wl1, const float* __restrict__ Wr1,
                                  unsigned short* __restrict__ Wt0, unsigned short* __restrict__ Wt1) {
    int idx = blockIdx.x * blockDim.x + threadIdx.x;
    if (idx < 384 * 128) {
        int c = idx >> 7, k = idx & 127;
        float v = (c < 192) ? Wl0[(size_t)k * 192 + c] : Wr0[(size_t)k * 192 + (c - 192)];
        Wt0[idx] = f2bf(v);
    } else if (idx < 384 * 128 + 128 * 192) {
        int i2 = idx - 384 * 128;
        int c = i2 / 192, k = i2 % 192;
        float v = (c < 64) ? Wl1[(size_t)k * 64 + c] : Wr1[(size_t)k * 64 + (c - 64)];
        Wt1[i2] = f2bf(v);
    }
}

// ---------------- CSR build (by dst) ----------------
__global__ void count_dst_kernel(const int* __restrict__ dst, int* __restrict__ counts, int E) {
    int e = blockIdx.x * blockDim.x + threadIdx.x;
    if (e < E) atomicAdd(&counts[dst[e]], 1);
}

// phase A: per-1024-chunk local exclusive scan; blkSum[b] = chunk total
__global__ void scanA_kernel(const int* __restrict__ counts, int* __restrict__ offs,
                             int* __restrict__ blkSum, int n) {
    __shared__ int wsum[4];
    const int lane = threadIdx.x & 63;
    const int wv = threadIdx.x >> 6;
    int i0 = blockIdx.x * 1024 + (int)threadIdx.x * 4;
    int v0 = (i0 + 0 < n) ? counts[i0 + 0] : 0;
    int v1 = (i0 + 1 < n) ? counts[i0 + 1] : 0;
    int v2 = (i0 + 2 < n) ? counts[i0 + 2] : 0;
    int v3 = (i0 + 3 < n) ? counts[i0 + 3] : 0;
    int s4 = v0 + v1 + v2 + v3;
    int s = s4;
    #pragma unroll
    for (int off = 1; off < 64; off <<= 1) {
        int t = __shfl_up(s, off, 64);
        if (lane >= off) s += t;
    }
    if (lane == 63) wsum[wv] = s;
    __syncthreads();
    int wpre = 0;
    for (int w = 0; w < wv; ++w) wpre += wsum[w];
    int excl = wpre + s - s4;
    if (i0 + 0 < n) offs[i0 + 0] = excl;
    excl += v0;
    if (i0 + 1 < n) offs[i0 + 1] = excl;
    excl += v1;
    if (i0 + 2 < n) offs[i0 + 2] = excl;
    excl += v2;
    if (i0 + 3 < n) offs[i0 + 3] = excl;
    if (threadIdx.x == 255) blkSum[blockIdx.x] = wpre + s;
}

// phase C (fused B): each block wave-reduces its blkSum prefix, adds to its chunk
__global__ void scanC_kernel(int* __restrict__ offs, const int* __restrict__ blkSum, int n, int E) {
    __shared__ int baseSh;
    const int b = blockIdx.x;
    if (threadIdx.x < 64) {
        int acc = 0;
        for (int i = threadIdx.x; i < b; i += 64) acc += blkSum[i];
        #pragma unroll
        for (int off = 1; off < 64; off <<= 1) acc += __shfl_xor(acc, off, 64);
        if (threadIdx.x == 0) baseSh = acc;
    }
    __syncthreads();
    const int base = baseSh;
    int i = b * 1024 + (int)threadIdx.x * 4;
    if (i + 3 < n) {
        int4 v = *reinterpret_cast<int4*>(&offs[i]);
        v.x += base; v.y += base; v.z += base; v.w += base;
        *reinterpret_cast<int4*>(&offs[i]) = v;
    } else {
        #pragma unroll
        for (int k = 0; k < 4; ++k)
            if (i + k < n) offs[i + k] += base;
    }
    if (b == 0 && threadIdx.x == 0) offs[n] = E;
}

__global__ void scatter_kernel(const int* __restrict__ src, const int* __restrict__ dst,
                               const int* __restrict__ offs, int* __restrict__ cursor,
                               int* __restrict__ esrc, int E) {
    int e = blockIdx.x * blockDim.x + threadIdx.x;
    if (e < E) {
        int d = dst[e];
        int pos = offs[d] + atomicAdd(&cursor[d], 1);
        esrc[pos] = src[e];
    }
}

// ---------------- MFMA dual GEMM ----------------
// out[:,0:NCH]=X@Wl+bl ; out[:,NCH:2NCH]=X@Wr+br (bf16 out). Wt: [2*NCH][K] bf16.
// BN=true: BN scale/shift computed in-block from stats (fused finalize), applied in A staging.
// Tile 128x128, 4 waves, 2x8 16x16x32 bf16 frags; LDS stride 40 (2-way conflicts = free).
template <int K, int NCH, bool BN>
__global__ __launch_bounds__(256) void mfma_dual_gemm(
    const float* __restrict__ X,
    const unsigned short* __restrict__ Wt,
    const float* __restrict__ bl, const float* __restrict__ br,
    const float* __restrict__ stats, const float* __restrict__ gamma,
    const float* __restrict__ beta, float invN,
    unsigned short* __restrict__ out, int N) {
    constexpr int ST = 2 * NCH;
    constexpr int LDA = 40;
    const int rowBase = blockIdx.x * 128;
    const int colBase = blockIdx.y * 128;

    __shared__ unsigned short XS[128 * LDA];
    __shared__ unsigned short WS[128 * LDA];
    __shared__ float ssA[K], ssB[K];

    const int tid = threadIdx.x;
    const int lane = tid & 63;
    const int wv = tid >> 6;
    const int lrow = lane & 15;
    const int lk = lane >> 4;

    if (BN) {
        for (int c = tid; c < K; c += 256) {
            float mu = stats[c] * invN;
            float var = stats[K + c] * invN - mu * mu;
            float sc = gamma[c] * rsqrtf(var + BN_EPS);
            ssA[c] = sc;
            ssB[c] = beta[c] - mu * sc;
        }
        __syncthreads();
    }

    float4v acc[2][8];
    #pragma unroll
    for (int i = 0; i < 2; ++i)
        #pragma unroll
        for (int j = 0; j < 8; ++j) acc[i][j] = (float4v){0.f, 0.f, 0.f, 0.f};

    for (int k0 = 0; k0 < K; k0 += 32) {
        {
            int r = tid >> 3;
            int kq = (tid & 7) * 4;
            float4 sc0, sc1;
            if (BN) {
                sc0 = *reinterpret_cast<const float4*>(&ssA[k0 + kq]);
                sc1 = *reinterpret_cast<const float4*>(&ssB[k0 + kq]);
            }
            #pragma unroll
            for (int i = 0; i < 4; ++i) {
                int row = r + 32 * i;
                int gr = rowBase + row;
                float4 v = make_float4(0.f, 0.f, 0.f, 0.f);
                if (gr < N) v = *reinterpret_cast<const float4*>(&X[(size_t)gr * K + k0 + kq]);
                if (BN) {
                    v.x = v.x * sc0.x + sc1.x;
                    v.y = v.y * sc0.y + sc1.y;
                    v.z = v.z * sc0.z + sc1.z;
                    v.w = v.w * sc0.w + sc1.w;
                }
                ushort4 u;
                u.x = f2bf(v.x); u.y = f2bf(v.y); u.z = f2bf(v.z); u.w = f2bf(v.w);
                *reinterpret_cast<ushort4*>(&XS[row * LDA + kq]) = u;
            }
        }
        {
            int c = tid >> 2;
            int kq8 = (tid & 3) * 8;
            #pragma unroll
            for (int i = 0; i < 2; ++i) {
                int col = c + 64 * i;
                uint4 w = *reinterpret_cast<const uint4*>(&Wt[(size_t)(colBase + col) * K + k0 + kq8]);
                *reinterpret_cast<uint4*>(&WS[col * LDA + kq8]) = w;
            }
        }
        __syncthreads();
        short8v aF[2], bF[8];
        #pragma unroll
        for (int rb = 0; rb < 2; ++rb)
            aF[rb] = *reinterpret_cast<const short8v*>(&XS[(wv * 32 + rb * 16 + lrow) * LDA + lk * 8]);
        #pragma unroll
        for (int cb = 0; cb < 8; ++cb)
            bF[cb] = *reinterpret_cast<const short8v*>(&WS[(cb * 16 + lrow) * LDA + lk * 8]);
        #pragma unroll
        for (int rb = 0; rb < 2; ++rb)
            #pragma unroll
            for (int cb = 0; cb < 8; ++cb)
                acc[rb][cb] = __builtin_amdgcn_mfma_f32_16x16x32_bf16(aF[rb], bF[cb], acc[rb][cb], 0, 0, 0);
        __syncthreads();
    }
    #pragma unroll
    for (int cb = 0; cb < 8; ++cb) {
        int cg = colBase + cb * 16 + lrow;
        float bv = (cg < NCH) ? bl[cg] : br[cg - NCH];
        #pragma unroll
        for (int rb = 0; rb < 2; ++rb) {
            #pragma unroll
            for (int r = 0; r < 4; ++r) {
                int row = rowBase + wv * 32 + rb * 16 + lk * 4 + r;
                if (row < N) out[(size_t)row * ST + cg] = f2bf(acc[rb][cb][r] + bv);
            }
        }
    }
}

// ---------------- GATv2 aggregation H=3: wave/node, 4 slots x 16 lanes x 4ch, prefetch d1 ----
template <int H>
__global__ __launch_bounds__(256) void gat_agg_kernel(
    const unsigned short* __restrict__ proj,
    const int* __restrict__ offs, const int* __restrict__ esrc,
    const float* __restrict__ att, const float* __restrict__ bias,
    float* __restrict__ outh, int N) {
    constexpr int C = 64;
    constexpr int HC = H * C;
    constexpr int ST = 2 * HC;
    const int lane = threadIdx.x & 63;
    const int node = blockIdx.x * 4 + (threadIdx.x >> 6);
    if (node >= N) return;
    const int j = lane >> 4;
    const int cg = (lane & 15) * 4;

    float4 xr4[H], att4[H], acc4[H];
    float den[H];
    #pragma unroll
    for (int h = 0; h < H; ++h) {
        ushort4 u = *reinterpret_cast<const ushort4*>(&proj[(size_t)node * ST + HC + h * C + cg]);
        xr4[h] = make_float4(bf2f(u.x), bf2f(u.y), bf2f(u.z), bf2f(u.w));
        att4[h] = *reinterpret_cast<const float4*>(&att[h * C + cg]);
        acc4[h] = make_float4(0.f, 0.f, 0.f, 0.f);
        den[h] = 0.f;
    }

    const int beg = offs[node];
    const int total = offs[node + 1] - beg + 1;  // virtual index 0 = self loop
    // prefetch iter 0 (clamped index is always a valid edge -> finite data)
    int vc0 = (j < total) ? j : (total - 1);
    int srcN = (vc0 == 0) ? node : esrc[beg + vc0 - 1];
    ushort4 uN[H];
    #pragma unroll
    for (int h = 0; h < H; ++h)
        uN[h] = *reinterpret_cast<const ushort4*>(&proj[(size_t)srcN * ST + h * C + cg]);

    for (int t = 0; t < total; t += 4) {
        ushort4 uC[H];
        #pragma unroll
        for (int h = 0; h < H; ++h) uC[h] = uN[h];
        const int v = t + j;
        const float w = (v < total) ? 1.f : 0.f;
        // prefetch next iteration (v2 >= 4 > 0: never the self-loop)
        const int v2 = v + 4;
        if (v2 < total) {
            int s2 = esrc[beg + v2 - 1];
            #pragma unroll
            for (int h = 0; h < H; ++h)
                uN[h] = *reinterpret_cast<const ushort4*>(&proj[(size_t)s2 * ST + h * C + cg]);
        }
        float4 xl4[H];
        float s[H];
        #pragma unroll
        for (int h = 0; h < H; ++h)
            xl4[h] = make_float4(bf2f(uC[h].x), bf2f(uC[h].y), bf2f(uC[h].z), bf2f(uC[h].w));
        #pragma unroll
        for (int h = 0; h < H; ++h) {
            float a0 = xl4[h].x + xr4[h].x;
            float a1 = xl4[h].y + xr4[h].y;
            float a2 = xl4[h].z + xr4[h].z;
            float a3 = xl4[h].w + xr4[h].w;
            a0 = (a0 > 0.f) ? a0 : LRELU_SLOPE * a0;
            a1 = (a1 > 0.f) ? a1 : LRELU_SLOPE * a1;
            a2 = (a2 > 0.f) ? a2 : LRELU_SLOPE * a2;
            a3 = (a3 > 0.f) ? a3 : LRELU_SLOPE * a3;
            s[h] = a0 * att4[h].x + a1 * att4[h].y + a2 * att4[h].z + a3 * att4[h].w;
        }
        #pragma unroll
        for (int off = 1; off <= 8; off <<= 1)
            #pragma unroll
            for (int h = 0; h < H; ++h) s[h] += __shfl_xor(s[h], off, 64);
        #pragma unroll
        for (int h = 0; h < H; ++h) {
            float p = w * __expf(s[h]);
            den[h] += p;
            acc4[h].x += p * xl4[h].x;
            acc4[h].y += p * xl4[h].y;
            acc4[h].z += p * xl4[h].z;
            acc4[h].w += p * xl4[h].w;
        }
    }

    #pragma unroll
    for (int off = 16; off <= 32; off <<= 1) {
        #pragma unroll
        for (int h = 0; h < H; ++h) {
            acc4[h].x += __shfl_xor(acc4[h].x, off, 64);
            acc4[h].y += __shfl_xor(acc4[h].y, off, 64);
            acc4[h].z += __shfl_xor(acc4[h].z, off, 64);
            acc4[h].w += __shfl_xor(acc4[h].w, off, 64);
            den[h]    += __shfl_xor(den[h],    off, 64);
        }
    }

    if (j == 0) {
        #pragma unroll
        for (int h = 0; h < H; ++h) {
            float4 b4 = *reinterpret_cast<const float4*>(&bias[h * C + cg]);
            float inv = 1.f / den[h];
            float4 o;
            o.x = acc4[h].x * inv + b4.x;
            o.y = acc4[h].y * inv + b4.y;
            o.z = acc4[h].z * inv + b4.z;
            o.w = acc4[h].w * inv + b4.w;
            o.x = (o.x > 0.f) ? o.x : 0.f;
            o.y = (o.y > 0.f) ? o.y : 0.f;
            o.z = (o.z > 0.f) ? o.z : 0.f;
            o.w = (o.w > 0.f) ? o.w : 0.f;
            *reinterpret_cast<float4*>(&outh[(size_t)node * HC + h * C + cg]) = o;
        }
    }
}

// ---------------- GATv2 aggregation H=1: 8 slots x 8 lanes x 8ch, uint4 gathers, prefetch ----
__global__ __launch_bounds__(256) void gat_agg1_kernel(
    const unsigned short* __restrict__ proj,  // [N,128] bf16 [xl|xr]
    const int* __restrict__ offs, const int* __restrict__ esrc,
    const float* __restrict__ att, const float* __restrict__ bias,
    float* __restrict__ outh, int N) {
    const int lane = threadIdx.x & 63;
    const int node = blockIdx.x * 4 + (threadIdx.x >> 6);
    if (node >= N) return;
    const int j = lane >> 3;        // slot 0..7
    const int cg = (lane & 7) * 8;  // channel base

    float xr[8], at[8], acc[8];
    float den = 0.f;
    {
        uint4 u = *reinterpret_cast<const uint4*>(&proj[(size_t)node * 128 + 64 + cg]);
        unpack2(u.x, xr[0], xr[1]); unpack2(u.y, xr[2], xr[3]);
        unpack2(u.z, xr[4], xr[5]); unpack2(u.w, xr[6], xr[7]);
        float4 a0 = *reinterpret_cast<const float4*>(&att[cg]);
        float4 a1 = *reinterpret_cast<const float4*>(&att[cg + 4]);
        at[0] = a0.x; at[1] = a0.y; at[2] = a0.z; at[3] = a0.w;
        at[4] = a1.x; at[5] = a1.y; at[6] = a1.z; at[7] = a1.w;
        #pragma unroll
        for (int c = 0; c < 8; ++c) acc[c] = 0.f;
    }

    const int beg = offs[node];
    const int total = offs[node + 1] - beg + 1;
    int vc0 = (j < total) ? j : (total - 1);
    int srcN = (vc0 == 0) ? node : esrc[beg + vc0 - 1];
    uint4 uN = *reinterpret_cast<const uint4*>(&proj[(size_t)srcN * 128 + cg]);

    for (int t = 0; t < total; t += 8) {
        uint4 uC = uN;
        const int v = t + j;
        const float w = (v < total) ? 1.f : 0.f;
        const int v2 = v + 8;
        if (v2 < total) {
            int s2 = esrc[beg + v2 - 1];
            uN = *reinterpret_cast<const uint4*>(&proj[(size_t)s2 * 128 + cg]);
        }
        float xl[8];
        unpack2(uC.x, xl[0], xl[1]); unpack2(uC.y, xl[2], xl[3]);
        unpack2(uC.z, xl[4], xl[5]); unpack2(uC.w, xl[6], xl[7]);
        float s = 0.f;
        #pragma unroll
        for (int c = 0; c < 8; ++c) {
            float a = xl[c] + xr[c];
            a = (a > 0.f) ? a : LRELU_SLOPE * a;
            s += a * at[c];
        }
        #pragma unroll
        for (int off = 1; off <= 4; off <<= 1) s += __shfl_xor(s, off, 64);
        float p = w * __expf(s);
        den += p;
        #pragma unroll
        for (int c = 0; c < 8; ++c) acc[c] += p * xl[c];
    }

    #pragma unroll
    for (int off = 8; off <= 32; off <<= 1) {
        den += __shfl_xor(den, off, 64);
        #pragma unroll
        for (int c = 0; c < 8; ++c) acc[c] += __shfl_xor(acc[c], off, 64);
    }

    if (j == 0) {
        float inv = 1.f / den;
        float4 b0 = *reinterpret_cast<const float4*>(&bias[cg]);
        float4 b1 = *reinterpret_cast<const float4*>(&bias[cg + 4]);
        float4 o0, o1;
        o0.x = acc[0] * inv + b0.x; o0.y = acc[1] * inv + b0.y;
        o0.z = acc[2] * inv + b0.z; o0.w = acc[3] * inv + b0.w;
        o1.x = acc[4] * inv + b1.x; o1.y = acc[5] * inv + b1.y;
        o1.z = acc[6] * inv + b1.z; o1.w = acc[7] * inv + b1.w;
        o0.x = (o0.x > 0.f) ? o0.x : 0.f; o0.y = (o0.y > 0.f) ? o0.y : 0.f;
        o0.z = (o0.z > 0.f) ? o0.z : 0.f; o0.w = (o0.w > 0.f) ? o0.w : 0.f;
        o1.x = (o1.x > 0.f) ? o1.x : 0.f; o1.y = (o1.y > 0.f) ? o1.y : 0.f;
        o1.z = (o1.z > 0.f) ? o1.z : 0.f; o1.w = (o1.w > 0.f) ? o1.w : 0.f;
        *reinterpret_cast<float4*>(&outh[(size_t)node * 64 + cg]) = o0;
        *reinterpret_cast<float4*>(&outh[(size_t)node * 64 + cg + 4]) = o1;
    }
}

// ---------------- BatchNorm stats ----------------
template <int CH>
__global__ void bn_stats_kernel(const float* __restrict__ h, float* __restrict__ stats, int N) {
    const int c = threadIdx.x;
    float s = 0.f, q = 0.f;
    for (int r = blockIdx.x; r < N; r += gridDim.x) {
        float v = h[(size_t)r * CH + c];
        s += v;
        q += v * v;
    }
    atomicAdd(&stats[c], s);
    atomicAdd(&stats[CH + c], q);
}

// fused finalize+apply for CH=64 (each thread recomputes its channels' scale)
__global__ void bn_finapply64_kernel(float* __restrict__ h, const float* __restrict__ stats,
                                     const float* __restrict__ gamma, const float* __restrict__ beta,
                                     float invN, size_t total4) {
    size_t i = (size_t)blockIdx.x * blockDim.x + threadIdx.x;
    if (i >= total4) return;
    size_t e = i * 4;
    int c = (int)(e & 63);
    float4 v = *reinterpret_cast<float4*>(&h[e]);
    #pragma unroll
    for (int k = 0; k < 4; ++k) {
        float mu = stats[c + k] * invN;
        float var = stats[64 + c + k] * invN - mu * mu;
        float sc = gamma[c + k] * rsqrtf(var + BN_EPS);
        (&v.x)[k] = ((&v.x)[k] - mu) * sc + beta[c + k];
    }
    *reinterpret_cast<float4*>(&h[e]) = v;
}

extern "C" void kernel_launch(void* const* d_in, const int* in_sizes, int n_in,
                              void* d_out, int out_size, void* d_ws, size_t ws_size,
                              hipStream_t stream) {
    const float* x     = (const float*)d_in[0];
    const int*   eidx  = (const int*)d_in[1];
    const float* Wl0   = (const float*)d_in[2];
    const float* bl0   = (const float*)d_in[3];
    const float* Wr0   = (const float*)d_in[4];
    const float* br0   = (const float*)d_in[5];
    const float* att0  = (const float*)d_in[6];
    const float* bias0 = (const float*)d_in[7];
    const float* g0    = (const float*)d_in[8];
    const float* be0   = (const float*)d_in[9];
    const float* Wl1   = (const float*)d_in[10];
    const float* bl1   = (const float*)d_in[11];
    const float* Wr1   = (const float*)d_in[12];
    const float* br1   = (const float*)d_in[13];
    const float* att1  = (const float*)d_in[14];
    const float* bias1 = (const float*)d_in[15];
    const float* g1    = (const float*)d_in[16];
    const float* be1   = (const float*)d_in[17];

    const int N = in_sizes[0] / 128;
    const int E = in_sizes[1] / 2;
    const int* srcIdx = eidx;
    const int* dstIdx = eidx + E;
    const int nChunks = (N + 1023) >> 10;
    const float invN = 1.f / (float)N;

    char* base = (char*)d_ws;
    auto alloc = [&](size_t bytes) {
        char* p = base;
        base += (bytes + 255) & ~(size_t)255;
        return p;
    };
    unsigned short* proj = (unsigned short*)alloc((size_t)N * 384 * 2);
    float* h0    = (float*)alloc((size_t)N * 192 * 4);
    int*   offs  = (int*)alloc((size_t)(N + 1) * 4);
    int*   esrc  = (int*)alloc((size_t)E * 4);
    int*   blkSum= (int*)alloc((size_t)nChunks * 4);
    unsigned short* Wt0 = (unsigned short*)alloc((size_t)384 * 128 * 2);
    unsigned short* Wt1 = (unsigned short*)alloc((size_t)128 * 192 * 2);
    // contiguous zero region: counts | cursor | stats0 | stats1
    char* zeroBeg = base;
    int*   counts = (int*)alloc((size_t)N * 4);
    int*   cursor = (int*)alloc((size_t)N * 4);
    float* stats0 = (float*)alloc(384 * 4);
    float* stats1 = (float*)alloc(128 * 4);
    size_t zeroBytes = (size_t)(base - zeroBeg);

    hipMemsetAsync(zeroBeg, 0, zeroBytes, stream);
    convert_w2_kernel<<<(384 * 128 + 128 * 192 + 255) / 256, 256, 0, stream>>>(Wl0, Wr0, Wl1, Wr1, Wt0, Wt1);

    // ---- CSR by dst ----
    count_dst_kernel<<<(E + 255) / 256, 256, 0, stream>>>(dstIdx, counts, E);
    scanA_kernel<<<nChunks, 256, 0, stream>>>(counts, offs, blkSum, N);
    scanC_kernel<<<nChunks, 256, 0, stream>>>(offs, blkSum, N, E);
    scatter_kernel<<<(E + 255) / 256, 256, 0, stream>>>(srcIdx, dstIdx, offs, cursor, esrc, E);

    // ---- layer 0: 128 -> 3x64 (concat 192) ----
    {
        dim3 grid((N + 127) / 128, 3);
        mfma_dual_gemm<128, 192, false><<<grid, 256, 0, stream>>>(
            x, Wt0, bl0, br0, nullptr, nullptr, nullptr, 0.f, proj, N);
    }
    gat_agg_kernel<3><<<(N + 3) / 4, 256, 0, stream>>>(proj, offs, esrc, att0, bias0, h0, N);
    bn_stats_kernel<192><<<256, 192, 0, stream>>>(h0, stats0, N);

    // ---- layer 1: 192 -> 1x64 (BN finalize+apply fused into A staging) ----
    {
        dim3 grid((N + 127) / 128, 1);
        mfma_dual_gemm<192, 64, true><<<grid, 256, 0, stream>>>(
            h0, Wt1, bl1, br1, stats0, g0, be0, invN, proj, N);
    }
    float* out = (float*)d_out;
    gat_agg1_kernel<<<(N + 3) / 4, 256, 0, stream>>>(proj, offs, esrc, att1, bias1, out, N);
    bn_stats_kernel<64><<<256, 64, 0, stream>>>(out, stats1, N);
    {
        size_t tot4 = (size_t)N * 16;
        bn_finapply64_kernel<<<(unsigned)((tot4 + 255) / 256), 256, 0, stream>>>(out, stats1, g1, be1, invN, tot4);
    }
}